// Round 1
// baseline (239.917 us; speedup 1.0000x reference)
//
#include <hip/hip_runtime.h>
#include <hip/hip_bf16.h>

// out[b, s, d] = in[b, s, d] + pe[s, d]
// pe[s, 2p]   = sin(s / 10000^(2p/1024))
// pe[s, 2p+1] = cos(s / 10000^(2p/1024))
//
// One thread per float4 of the (S, D) plane; loop over the batch dim so the
// 2 sincosf per thread amortize over 8 * 32 B of memory traffic.

#define SEQ_LEN 4096
#define D_MODEL 1024

__global__ void __launch_bounds__(256)
pe_add_kernel(const float* __restrict__ in, float* __restrict__ out, int batch) {
    constexpr int D4 = D_MODEL / 4;                  // float4s per row = 256
    constexpr long long PLANE = (long long)SEQ_LEN * D_MODEL;

    int idx = blockIdx.x * blockDim.x + threadIdx.x; // 0 .. SEQ_LEN*D4-1
    if (idx >= SEQ_LEN * D4) return;

    int d4 = idx & (D4 - 1);     // which float4 within the row
    int s  = idx >> 8;           // row index (D4 == 256 == 2^8)

    // pair indices covered by this float4: p0 = 2*d4, p1 = 2*d4+1
    // angle(p) = s * 10000^(-2p/1024) = s * exp2(-p * (2/1024) * log2(10000))
    constexpr float K = -0.025952563241307517f;      // -(2/1024)*log2(10000)
    float sf = (float)s;
    int   p0 = d4 * 2;
    float ang0 = sf * exp2f((float)p0 * K);
    float ang1 = sf * exp2f((float)(p0 + 1) * K);

    float s0, c0, s1, c1;
    sincosf(ang0, &s0, &c0);
    sincosf(ang1, &s1, &c1);
    float4 pe = make_float4(s0, c0, s1, c1);

    long long off = (long long)idx * 4;
    #pragma unroll
    for (int b = 0; b < 8; ++b) {
        const float4* src = reinterpret_cast<const float4*>(in  + (long long)b * PLANE + off);
        float4*       dst = reinterpret_cast<float4*>      (out + (long long)b * PLANE + off);
        float4 v = *src;
        v.x += pe.x; v.y += pe.y; v.z += pe.z; v.w += pe.w;
        *dst = v;
    }
}

extern "C" void kernel_launch(void* const* d_in, const int* in_sizes, int n_in,
                              void* d_out, int out_size, void* d_ws, size_t ws_size,
                              hipStream_t stream) {
    const float* in  = (const float*)d_in[0];
    float*       out = (float*)d_out;
    int batch = in_sizes[0] / (SEQ_LEN * D_MODEL);   // = 8

    constexpr int THREADS = SEQ_LEN * (D_MODEL / 4); // 1,048,576
    dim3 block(256);
    dim3 grid((THREADS + 255) / 256);                // 4096 blocks
    pe_add_kernel<<<grid, block, 0, stream>>>(in, out, batch);
}